// Round 2
// baseline (1673.272 us; speedup 1.0000x reference)
//
#include <hip/hip_runtime.h>

// WadaIN modulated conv1d, fp32, fully fused (round 2).
// B=16, CIN=COUT=256, K=5, SPK=128, T=8192, reflect pad 2.
// out = leaky_relu(conv1d(x_pad, demod(weight * style)), 0.2); second output = c_trg.
//
// R1 post-mortem: d_ws overflow suspected (used 295 KB without checking ws_size;
// first validation passed, replays diverged => pristine-input corruption pattern).
// Fix: no workspace at all — style/demod fused into the conv kernel prologue.

#define B_   16
#define CIN  256
#define COUT 256
#define KW   5
#define SPK  128
#define TT   8192
#define PADW 2

// conv tile config
#define MO   32    // output channels per block
#define NTT  256   // time samples per block
#define BKC  32    // input channels per LDS chunk

__global__ __launch_bounds__(256) void conv_kernel(
    const float* __restrict__ x, const float* __restrict__ c_trg,
    const float* __restrict__ style_w, const float* __restrict__ style_b,
    const float* __restrict__ weight, float* __restrict__ out)
{
    __shared__ float xs[BKC][NTT + 4];      // 32 x 260 (row 1040 B, 16B aligned)
    __shared__ float wsm[BKC][MO * KW];     // 32 x 160 (row 640 B, 16B aligned)
    __shared__ float s_sh[CIN];             // modulation per input channel
    __shared__ float dmv[MO];               // demod per output channel (this block)
    __shared__ float c_sh[SPK];

    const int b   = blockIdx.z;
    const int o0  = blockIdx.y * MO;
    const int t0  = blockIdx.x * NTT;
    const int tid = threadIdx.x;

    // ---- prologue: style s[i] = c_trg[b] . style_w[i] + style_b[i] ----
    if (tid < SPK) c_sh[tid] = c_trg[b * SPK + tid];
    __syncthreads();
    {
        float acc = style_b[tid];
        const float* wr = style_w + (size_t)tid * SPK;
        #pragma unroll 4
        for (int j = 0; j < SPK; ++j) acc += c_sh[j] * wr[j];
        s_sh[tid] = acc;
    }
    __syncthreads();

    // ---- prologue: demod for this block's 32 output channels ----
    // 8 threads per o; each covers 32 input channels; shfl-reduce within 8 lanes.
    {
        const int o_l  = tid >> 3;          // 0..31
        const int seg  = tid & 7;           // 0..7
        const int o    = o0 + o_l;
        float a = 0.f;
        const float* wbase = weight + ((size_t)o * CIN + seg * 32) * KW;
        #pragma unroll 4
        for (int i = 0; i < 32; ++i) {
            const float* wp = wbase + i * KW;
            float w2 = wp[0]*wp[0] + wp[1]*wp[1] + wp[2]*wp[2]
                     + wp[3]*wp[3] + wp[4]*wp[4];
            float sv = s_sh[seg * 32 + i];
            a += w2 * sv * sv;
        }
        a += __shfl_down(a, 4, 8);
        a += __shfl_down(a, 2, 8);
        a += __shfl_down(a, 1, 8);
        if (seg == 0) dmv[o_l] = rsqrtf(a + 1e-8f);
    }
    __syncthreads();

    // ---- main conv loop ----
    const int o_grp = tid >> 5;   // 0..7, 4 o each
    const int t_grp = tid & 31;   // 0..31, 8 t each
    const int tb    = t_grp * 8;

    float acc[4][8];
    #pragma unroll
    for (int a = 0; a < 4; ++a)
        #pragma unroll
        for (int j = 0; j < 8; ++j) acc[a][j] = 0.f;

    const float* xb = x + (size_t)b * CIN * TT;

    for (int c = 0; c < CIN; c += BKC) {
        __syncthreads();
        // stage x slab (with reflect padding)
        for (int idx = tid; idx < BKC * (NTT + 4); idx += 256) {
            int ii = idx / (NTT + 4);
            int j  = idx - ii * (NTT + 4);
            int tg = t0 + j - PADW;
            tg = (tg < 0) ? -tg : tg;
            tg = (tg > TT - 1) ? (2 * (TT - 1) - tg) : tg;
            xs[ii][j] = xb[(size_t)(c + ii) * TT + tg];
        }
        // stage modulated weights: wsm[ii][o*KW+k] = w[o0+o, c+ii, k]*s[c+ii]*dm[o]
        for (int idx = tid; idx < BKC * MO * KW; idx += 256) {
            int ii = idx / (MO * KW);
            int r  = idx - ii * (MO * KW);
            int o  = r / KW;
            int k  = r - o * KW;
            float wv = weight[(size_t)(o0 + o) * (CIN * KW) + (c + ii) * KW + k];
            wsm[ii][r] = wv * s_sh[c + ii] * dmv[o];
        }
        __syncthreads();

        #pragma unroll 2
        for (int ii = 0; ii < BKC; ++ii) {
            float xv[12];
            *(float4*)&xv[0] = *(const float4*)&xs[ii][tb];
            *(float4*)&xv[4] = *(const float4*)&xs[ii][tb + 4];
            *(float4*)&xv[8] = *(const float4*)&xs[ii][tb + 8];
            float wv[20];
            const float4* wrow4 = (const float4*)&wsm[ii][o_grp * 4 * KW];
            #pragma unroll
            for (int q = 0; q < 5; ++q) ((float4*)wv)[q] = wrow4[q];
            #pragma unroll
            for (int a = 0; a < 4; ++a) {
                #pragma unroll
                for (int j = 0; j < 8; ++j) {
                    float t = acc[a][j];
                    t += wv[a * KW + 0] * xv[j + 0];
                    t += wv[a * KW + 1] * xv[j + 1];
                    t += wv[a * KW + 2] * xv[j + 2];
                    t += wv[a * KW + 3] * xv[j + 3];
                    t += wv[a * KW + 4] * xv[j + 4];
                    acc[a][j] = t;
                }
            }
        }
    }

    // ---- epilogue: leaky relu + store ----
    #pragma unroll
    for (int a = 0; a < 4; ++a) {
        const int o = o0 + o_grp * 4 + a;
        float* po = out + ((size_t)b * COUT + o) * TT + t0 + tb;
        #pragma unroll
        for (int j = 0; j < 8; j += 4) {
            float4 v;
            v.x = acc[a][j + 0] > 0.f ? acc[a][j + 0] : 0.2f * acc[a][j + 0];
            v.y = acc[a][j + 1] > 0.f ? acc[a][j + 1] : 0.2f * acc[a][j + 1];
            v.z = acc[a][j + 2] > 0.f ? acc[a][j + 2] : 0.2f * acc[a][j + 2];
            v.w = acc[a][j + 3] > 0.f ? acc[a][j + 3] : 0.2f * acc[a][j + 3];
            *(float4*)&po[j] = v;
        }
    }
}

// ---------------------------------------------------------------------------
extern "C" void kernel_launch(void* const* d_in, const int* in_sizes, int n_in,
                              void* d_out, int out_size, void* d_ws, size_t ws_size,
                              hipStream_t stream)
{
    const float* x       = (const float*)d_in[0];
    const float* c_trg   = (const float*)d_in[1];
    const float* style_w = (const float*)d_in[2];
    const float* style_b = (const float*)d_in[3];
    const float* weight  = (const float*)d_in[4];
    float* out = (float*)d_out;

    conv_kernel<<<dim3(TT / NTT, COUT / MO, B_), dim3(256), 0, stream>>>(
        x, c_trg, style_w, style_b, weight, out);

    // second tuple output: c_trg passthrough
    hipMemcpyAsync(out + (size_t)B_ * COUT * TT, c_trg,
                   (size_t)B_ * SPK * sizeof(float),
                   hipMemcpyDeviceToDevice, stream);
}

// Round 3
// 418.738 us; speedup vs baseline: 3.9960x; 3.9960x over previous
//
#include <hip/hip_runtime.h>

// WadaIN modulated conv1d — bf16 MFMA rewrite (round 3).
// out[b,o,t] = leaky_relu( dm[b,o] * sum_{i,k} (w[o,i,k]*s[b,i]) * x[b,i,t+k-2], 0.2 )
// dm = rsqrt(sum_{i,k} (w*s)^2 + 1e-8), reflect pad, second output = c_trg.
//
// GEMM view per b: M=o(256 over 2 tiles of 128), N=t(8192 over 64 tiles of 128),
// K=(i,tap)=1280. Block: 4 waves, each 64x64 via 4x4 frags of mfma_f32_16x16x32_bf16.
// K-chunk = 32 input channels; per tap one K=32 MFMA step.
// x_sh [t=136][i=32] bf16, XOR-swizzled at 16B granularity: phys_grp = (i/8) ^ (t&3).
// w_sh [tap=5][o=128][i=32] bf16 (modulated by s only; demod applied in epilogue).

#define B_    16
#define CIN   256
#define COUT  256
#define KW    5
#define SPK   128
#define TT    8192

#define OM    128   // o per block
#define TN    128   // t per block
#define BI    32    // input channels per K-chunk
#define NCH   (CIN / BI)   // 8 chunks

typedef __attribute__((ext_vector_type(8))) short short8;
typedef __attribute__((ext_vector_type(4))) float f32x4;
typedef unsigned short ushort_t;
typedef unsigned int uint_t;

__device__ __forceinline__ ushort_t f2bf(float f) {
    uint_t u = __float_as_uint(f);
    u += 0x7FFF + ((u >> 16) & 1);   // RNE
    return (ushort_t)(u >> 16);
}

__global__ __launch_bounds__(256, 3) void conv_mfma_kernel(
    const float* __restrict__ x, const float* __restrict__ c_trg,
    const float* __restrict__ style_w, const float* __restrict__ style_b,
    const float* __restrict__ weight, float* __restrict__ out)
{
    __shared__ ushort_t x_sh[136 * 32];       // 8704 B, row stride 32 shorts (64 B)
    __shared__ ushort_t w_sh[KW * OM * 32];   // 40960 B
    __shared__ float    c_sh[SPK];
    __shared__ float    s_sh[CIN];
    __shared__ float    dm_acc[OM];
    __shared__ float    dmv[OM];

    const int b   = blockIdx.z;
    const int o0  = blockIdx.y * OM;
    const int t0  = blockIdx.x * TN;
    const int tid = threadIdx.x;

    const int lane  = tid & 63;
    const int wv    = tid >> 6;       // 0..3
    const int wm    = wv >> 1;        // o-half of block tile
    const int wn    = wv & 1;         // t-half
    const int col16 = lane & 15;
    const int quad  = lane >> 4;      // 0..3

    // ---------------- prologue: style + init ----------------
    if (tid < SPK) c_sh[tid] = c_trg[b * SPK + tid];
    if (tid < OM)  dm_acc[tid] = 0.f;
    __syncthreads();
    {
        float acc = style_b[tid];
        const float* wr = style_w + (size_t)tid * SPK;
        #pragma unroll 4
        for (int j = 0; j < SPK; ++j) acc += c_sh[j] * wr[j];
        s_sh[tid] = acc;
    }
    // (no barrier needed yet: first use of s_sh is after the next __syncthreads)

    f32x4 acc[4][4];
    #pragma unroll
    for (int mt = 0; mt < 4; ++mt)
        #pragma unroll
        for (int nt = 0; nt < 4; ++nt)
            acc[mt][nt] = (f32x4){0.f, 0.f, 0.f, 0.f};

    const float* xb = x + (size_t)b * CIN * TT;

    // ---------------- K loop over 8 chunks of 32 channels ----------------
    for (int ch = 0; ch < NCH; ++ch) {
        const int i0 = ch * BI;
        __syncthreads();   // previous chunk's MFMA reads done (also covers s_sh/dm_acc init)

        // ---- stage x: rows r=0..135 <-> global t = t0 + r - 2 (reflect), 32 ch ----
        {
            const int i4 = tid >> 5;           // 0..7 -> 4 channels each
            const int rl = tid & 31;
            const float* xp = xb + (size_t)(i0 + i4 * 4) * TT;
            #pragma unroll
            for (int rr = 0; rr < 136; rr += 32) {
                int r = rr + rl;
                if (r < 136) {
                    int tg = t0 + r - 2;
                    tg = (tg < 0) ? -tg : tg;
                    tg = (tg > TT - 1) ? (2 * (TT - 1) - tg) : tg;
                    float v0 = xp[tg];
                    float v1 = xp[TT + tg];
                    float v2 = xp[2 * TT + tg];
                    float v3 = xp[3 * TT + tg];
                    union { ushort_t us[4]; uint2 u2; } p;
                    p.us[0] = f2bf(v0); p.us[1] = f2bf(v1);
                    p.us[2] = f2bf(v2); p.us[3] = f2bf(v3);
                    int grp = (i4 >> 1) ^ (r & 3);
                    *(uint2*)&x_sh[r * 32 + grp * 8 + (i4 & 1) * 4] = p.u2;
                }
            }
        }

        // ---- stage w: modulated by s, accumulate (w*s)^2 into dm_acc ----
        {
            const int i4 = tid & 7;            // 4 channels each
            #pragma unroll
            for (int pass = 0; pass < 4; ++pass) {
                const int o_l = (tid >> 3) + pass * 32;   // 0..127
                const float* wp = weight + ((size_t)(o0 + o_l) * CIN + i0 + i4 * 4) * KW;
                float q[20];
                #pragma unroll
                for (int f = 0; f < 5; ++f)
                    *(float4*)&q[f * 4] = *(const float4*)(wp + f * 4);
                float sv0 = s_sh[i0 + i4 * 4 + 0];
                float sv1 = s_sh[i0 + i4 * 4 + 1];
                float sv2 = s_sh[i0 + i4 * 4 + 2];
                float sv3 = s_sh[i0 + i4 * 4 + 3];
                float m0[5], m1[5], m2[5], m3[5];
                float psum = 0.f;
                #pragma unroll
                for (int k = 0; k < 5; ++k) {
                    m0[k] = q[0 * 5 + k] * sv0;  psum += m0[k] * m0[k];
                    m1[k] = q[1 * 5 + k] * sv1;  psum += m1[k] * m1[k];
                    m2[k] = q[2 * 5 + k] * sv2;  psum += m2[k] * m2[k];
                    m3[k] = q[3 * 5 + k] * sv3;  psum += m3[k] * m3[k];
                }
                atomicAdd(&dm_acc[o_l], psum);
                #pragma unroll
                for (int k = 0; k < 5; ++k) {
                    union { ushort_t us[4]; uint2 u2; } p;
                    p.us[0] = f2bf(m0[k]); p.us[1] = f2bf(m1[k]);
                    p.us[2] = f2bf(m2[k]); p.us[3] = f2bf(m3[k]);
                    *(uint2*)&w_sh[(k * OM + o_l) * 32 + i4 * 4] = p.u2;
                }
            }
        }

        __syncthreads();

        // ---- MFMA: 5 taps x (4 A-frags, 4 B-frags, 16 mfma) ----
        #pragma unroll
        for (int kt = 0; kt < KW; ++kt) {
            short8 a[4], bf[4];
            #pragma unroll
            for (int mt = 0; mt < 4; ++mt)
                a[mt] = *(const short8*)&w_sh[(kt * OM + wm * 64 + mt * 16 + col16) * 32 + quad * 8];
            #pragma unroll
            for (int nt = 0; nt < 4; ++nt) {
                int r   = wn * 64 + nt * 16 + col16 + kt;   // 0..131
                int grp = quad ^ (r & 3);
                bf[nt] = *(const short8*)&x_sh[r * 32 + grp * 8];
            }
            #pragma unroll
            for (int mt = 0; mt < 4; ++mt)
                #pragma unroll
                for (int nt = 0; nt < 4; ++nt)
                    acc[mt][nt] = __builtin_amdgcn_mfma_f32_16x16x32_bf16(
                        a[mt], bf[nt], acc[mt][nt], 0, 0, 0);
        }
    }

    // ---------------- epilogue: demod + leaky relu + store ----------------
    __syncthreads();
    if (tid < OM) dmv[tid] = rsqrtf(dm_acc[tid] + 1e-8f);
    __syncthreads();

    #pragma unroll
    for (int mt = 0; mt < 4; ++mt) {
        #pragma unroll
        for (int nt = 0; nt < 4; ++nt) {
            const int t_o = t0 + wn * 64 + nt * 16 + col16;
            #pragma unroll
            for (int reg = 0; reg < 4; ++reg) {
                const int o_l = wm * 64 + mt * 16 + quad * 4 + reg;
                float v = acc[mt][nt][reg] * dmv[o_l];
                v = (v > 0.f) ? v : 0.2f * v;
                out[((size_t)(b * COUT + o0 + o_l)) * TT + t_o] = v;
            }
        }
    }
}

// ---------------------------------------------------------------------------
extern "C" void kernel_launch(void* const* d_in, const int* in_sizes, int n_in,
                              void* d_out, int out_size, void* d_ws, size_t ws_size,
                              hipStream_t stream)
{
    const float* x       = (const float*)d_in[0];
    const float* c_trg   = (const float*)d_in[1];
    const float* style_w = (const float*)d_in[2];
    const float* style_b = (const float*)d_in[3];
    const float* weight  = (const float*)d_in[4];
    float* out = (float*)d_out;

    conv_mfma_kernel<<<dim3(TT / TN, COUT / OM, B_), dim3(256), 0, stream>>>(
        x, c_trg, style_w, style_b, weight, out);

    hipMemcpyAsync(out + (size_t)B_ * COUT * TT, c_trg,
                   (size_t)B_ * SPK * sizeof(float),
                   hipMemcpyDeviceToDevice, stream);
}

// Round 4
// 314.474 us; speedup vs baseline: 5.3209x; 1.3315x over previous
//
#include <hip/hip_runtime.h>

// WadaIN modulated conv1d — round 4: precomputed bf16 weights in d_ws.
// Fast path (ws_size >= 10.49MB):
//   prep_kernel: s = c_trg@style_w^T + b; dm = rsqrt(sum (w*s)^2 + 1e-8);
//                wmod[b][ot][ch][k][o_l 128][i 32] = bf16(w * s * dm)  (conv-LDS layout)
//   conv_mfma_ws_kernel: stages wmod via global_load_lds (width 16, zero VALU),
//                stages x (f2bf + XOR swizzle), 5-tap MFMA K-loop, leaky-relu store.
// Fallback (small ws): R3 kernel verbatim (fully fused, no workspace).
// Branch on ws_size is deterministic across calls -> graph-capture safe.

#define B_    16
#define CIN   256
#define COUT  256
#define KW    5
#define SPK   128
#define TT    8192

#define OM    128   // o per block
#define TN    128   // t per block
#define BI    32    // input channels per K-chunk
#define NCH   (CIN / BI)   // 8

#define WSLAB (KW * OM * 32)                       // 20480 ushorts per (b,ot,ch)
#define WMOD_BYTES ((size_t)B_ * 2 * NCH * WSLAB * 2)  // 10,485,760 B

typedef __attribute__((ext_vector_type(8))) short short8;
typedef __attribute__((ext_vector_type(4))) float f32x4;
typedef unsigned short ushort_t;
typedef unsigned int uint_t;

__device__ __forceinline__ ushort_t f2bf(float f) {
    uint_t u = __float_as_uint(f);
    u += 0x7FFF + ((u >> 16) & 1);   // RNE
    return (ushort_t)(u >> 16);
}

// ---------------------------------------------------------------------------
// prep: grid (32 og, 16 b), 256 thr. Each block: 8 output channels.
__global__ __launch_bounds__(256) void prep_kernel(
    const float* __restrict__ c_trg, const float* __restrict__ style_w,
    const float* __restrict__ style_b, const float* __restrict__ weight,
    ushort_t* __restrict__ wmod)
{
    __shared__ float c_sh[SPK];
    __shared__ float s_sh[CIN];
    __shared__ float w_l[8 * 1280];     // 8 o x (256 i x 5 k), 40960 B
    __shared__ float dm_sh[8];

    const int og  = blockIdx.x;        // 0..31 -> o = og*8 .. og*8+7
    const int b   = blockIdx.y;
    const int tid = threadIdx.x;

    if (tid < SPK) c_sh[tid] = c_trg[b * SPK + tid];
    __syncthreads();
    {
        float acc = style_b[tid];
        const float* wr = style_w + (size_t)tid * SPK;
        #pragma unroll 4
        for (int j = 0; j < SPK; ++j) acc += c_sh[j] * wr[j];
        s_sh[tid] = acc;
    }
    // stage 8-o weight slab (contiguous 40960 B), coalesced float4
    {
        const float* wsrc = weight + (size_t)og * 8 * 1280;
        #pragma unroll
        for (int it = 0; it < 10; ++it)
            *(float4*)&w_l[(it * 256 + tid) * 4] = *(const float4*)&wsrc[(it * 256 + tid) * 4];
    }
    __syncthreads();

    // demod: 32 threads per o, elements j = part + 32m, i = j/5
    {
        const int oi   = tid >> 5;
        const int part = tid & 31;
        float a = 0.f;
        #pragma unroll 8
        for (int m = 0; m < 40; ++m) {
            int j = part + m * 32;
            float v = w_l[oi * 1280 + j] * s_sh[j / 5];
            a += v * v;
        }
        a += __shfl_xor(a, 16);
        a += __shfl_xor(a, 8);
        a += __shfl_xor(a, 4);
        a += __shfl_xor(a, 2);
        a += __shfl_xor(a, 1);
        if (part == 0) dm_sh[oi] = rsqrtf(a + 1e-8f);
    }
    __syncthreads();

    // write wmod rows: 320 rows of 32 i (64 B each)
    for (int r = tid; r < 320; r += 256) {
        const int oi  = r / 40;
        const int rem = r - oi * 40;
        const int ch  = rem / 5;
        const int k   = rem - ch * 5;
        const int o   = og * 8 + oi;
        const int ot  = o >> 7;
        const int o_l = o & 127;
        const float dmv = dm_sh[oi];
        ushort_t* dst = wmod + ((((size_t)(b * 2 + ot) * NCH + ch) * KW + k) * OM + o_l) * 32;
        #pragma unroll
        for (int g = 0; g < 4; ++g) {
            union { ushort_t us[8]; uint4 v; } pk;
            #pragma unroll
            for (int ii = 0; ii < 8; ++ii) {
                int i_l = g * 8 + ii;
                int i_g = ch * 32 + i_l;
                pk.us[ii] = f2bf(w_l[oi * 1280 + i_g * 5 + k] * s_sh[i_g] * dmv);
            }
            *(uint4*)&dst[g * 8] = pk.v;
        }
    }
}

// ---------------------------------------------------------------------------
// fast conv: weights from wmod via global_load_lds; demod already folded.
__global__ __launch_bounds__(256, 3) void conv_mfma_ws_kernel(
    const float* __restrict__ x, const ushort_t* __restrict__ wmod,
    float* __restrict__ out)
{
    __shared__ __align__(16) ushort_t x_sh[136 * 32];   // 8704 B, XOR-swizzled
    __shared__ __align__(16) ushort_t w_sh[WSLAB];      // 40960 B

    const int b   = blockIdx.z;
    const int ot  = blockIdx.y;
    const int o0  = ot * OM;
    const int t0  = blockIdx.x * TN;
    const int tid = threadIdx.x;

    const int lane  = tid & 63;
    const int wv    = tid >> 6;
    const int wm    = wv >> 1;
    const int wn    = wv & 1;
    const int col16 = lane & 15;
    const int quad  = lane >> 4;

    f32x4 acc[4][4];
    #pragma unroll
    for (int mt = 0; mt < 4; ++mt)
        #pragma unroll
        for (int nt = 0; nt < 4; ++nt)
            acc[mt][nt] = (f32x4){0.f, 0.f, 0.f, 0.f};

    const float* xb = x + (size_t)b * CIN * TT;
    const ushort_t* wslab = wmod + (size_t)(b * 2 + ot) * NCH * WSLAB;

    for (int ch = 0; ch < NCH; ++ch) {
        const int i0 = ch * BI;
        __syncthreads();

        // ---- async stage w: 40960 B, 10 x 16B per lane, zero VALU math ----
        {
            const ushort_t* ws = wslab + (size_t)ch * WSLAB;
            #pragma unroll
            for (int it = 0; it < 10; ++it) {
                const int off = it * 2048 + wv * 512;   // ushort units; 16B/lane
                __builtin_amdgcn_global_load_lds(
                    (const __attribute__((address_space(1))) uint_t*)(ws + off + lane * 8),
                    (__attribute__((address_space(3))) uint_t*)(&w_sh[off]),
                    16, 0, 0);
            }
        }

        // ---- stage x: rows r=0..135 <-> t = t0 + r - 2 (reflect), 32 ch ----
        {
            const int i4 = tid >> 5;           // 4 channels each
            const int rl = tid & 31;
            const float* xp = xb + (size_t)(i0 + i4 * 4) * TT;
            #pragma unroll
            for (int rr = 0; rr < 136; rr += 32) {
                int r = rr + rl;
                if (r < 136) {
                    int tg = t0 + r - 2;
                    tg = (tg < 0) ? -tg : tg;
                    tg = (tg > TT - 1) ? (2 * (TT - 1) - tg) : tg;
                    float v0 = xp[tg];
                    float v1 = xp[TT + tg];
                    float v2 = xp[2 * TT + tg];
                    float v3 = xp[3 * TT + tg];
                    union { ushort_t us[4]; uint2 u2; } p;
                    p.us[0] = f2bf(v0); p.us[1] = f2bf(v1);
                    p.us[2] = f2bf(v2); p.us[3] = f2bf(v3);
                    int grp = (i4 >> 1) ^ (r & 3);
                    *(uint2*)&x_sh[r * 32 + grp * 8 + (i4 & 1) * 4] = p.u2;
                }
            }
        }

        __syncthreads();

        // ---- MFMA: 5 taps x 16 mfma ----
        #pragma unroll
        for (int kt = 0; kt < KW; ++kt) {
            short8 a[4], bf[4];
            #pragma unroll
            for (int mt = 0; mt < 4; ++mt)
                a[mt] = *(const short8*)&w_sh[(kt * OM + wm * 64 + mt * 16 + col16) * 32 + quad * 8];
            #pragma unroll
            for (int nt = 0; nt < 4; ++nt) {
                int r   = wn * 64 + nt * 16 + col16 + kt;
                int grp = quad ^ (r & 3);
                bf[nt] = *(const short8*)&x_sh[r * 32 + grp * 8];
            }
            #pragma unroll
            for (int mt = 0; mt < 4; ++mt)
                #pragma unroll
                for (int nt = 0; nt < 4; ++nt)
                    acc[mt][nt] = __builtin_amdgcn_mfma_f32_16x16x32_bf16(
                        a[mt], bf[nt], acc[mt][nt], 0, 0, 0);
        }
    }

    // ---- epilogue: leaky relu + store (demod pre-folded) ----
    #pragma unroll
    for (int mt = 0; mt < 4; ++mt) {
        #pragma unroll
        for (int nt = 0; nt < 4; ++nt) {
            const int t_o = t0 + wn * 64 + nt * 16 + col16;
            #pragma unroll
            for (int reg = 0; reg < 4; ++reg) {
                const int o_l = wm * 64 + mt * 16 + quad * 4 + reg;
                float v = acc[mt][nt][reg];
                v = (v > 0.f) ? v : 0.2f * v;
                out[((size_t)(b * COUT + o0 + o_l)) * TT + t_o] = v;
            }
        }
    }
}

// ---------------------------------------------------------------------------
// Fallback: R3 kernel verbatim (no workspace), known-good at ~419 us.
__global__ __launch_bounds__(256, 3) void conv_mfma_fb_kernel(
    const float* __restrict__ x, const float* __restrict__ c_trg,
    const float* __restrict__ style_w, const float* __restrict__ style_b,
    const float* __restrict__ weight, float* __restrict__ out)
{
    __shared__ ushort_t x_sh[136 * 32];
    __shared__ ushort_t w_sh[KW * OM * 32];
    __shared__ float    c_sh[SPK];
    __shared__ float    s_sh[CIN];
    __shared__ float    dm_acc[OM];
    __shared__ float    dmv[OM];

    const int b   = blockIdx.z;
    const int o0  = blockIdx.y * OM;
    const int t0  = blockIdx.x * TN;
    const int tid = threadIdx.x;

    const int lane  = tid & 63;
    const int wv    = tid >> 6;
    const int wm    = wv >> 1;
    const int wn    = wv & 1;
    const int col16 = lane & 15;
    const int quad  = lane >> 4;

    if (tid < SPK) c_sh[tid] = c_trg[b * SPK + tid];
    if (tid < OM)  dm_acc[tid] = 0.f;
    __syncthreads();
    {
        float acc = style_b[tid];
        const float* wr = style_w + (size_t)tid * SPK;
        #pragma unroll 4
        for (int j = 0; j < SPK; ++j) acc += c_sh[j] * wr[j];
        s_sh[tid] = acc;
    }

    f32x4 acc[4][4];
    #pragma unroll
    for (int mt = 0; mt < 4; ++mt)
        #pragma unroll
        for (int nt = 0; nt < 4; ++nt)
            acc[mt][nt] = (f32x4){0.f, 0.f, 0.f, 0.f};

    const float* xb = x + (size_t)b * CIN * TT;

    for (int ch = 0; ch < NCH; ++ch) {
        const int i0 = ch * BI;
        __syncthreads();
        {
            const int i4 = tid >> 5;
            const int rl = tid & 31;
            const float* xp = xb + (size_t)(i0 + i4 * 4) * TT;
            #pragma unroll
            for (int rr = 0; rr < 136; rr += 32) {
                int r = rr + rl;
                if (r < 136) {
                    int tg = t0 + r - 2;
                    tg = (tg < 0) ? -tg : tg;
                    tg = (tg > TT - 1) ? (2 * (TT - 1) - tg) : tg;
                    float v0 = xp[tg];
                    float v1 = xp[TT + tg];
                    float v2 = xp[2 * TT + tg];
                    float v3 = xp[3 * TT + tg];
                    union { ushort_t us[4]; uint2 u2; } p;
                    p.us[0] = f2bf(v0); p.us[1] = f2bf(v1);
                    p.us[2] = f2bf(v2); p.us[3] = f2bf(v3);
                    int grp = (i4 >> 1) ^ (r & 3);
                    *(uint2*)&x_sh[r * 32 + grp * 8 + (i4 & 1) * 4] = p.u2;
                }
            }
        }
        {
            const int i4 = tid & 7;
            #pragma unroll
            for (int pass = 0; pass < 4; ++pass) {
                const int o_l = (tid >> 3) + pass * 32;
                const float* wp = weight + ((size_t)(o0 + o_l) * CIN + i0 + i4 * 4) * KW;
                float q[20];
                #pragma unroll
                for (int f = 0; f < 5; ++f)
                    *(float4*)&q[f * 4] = *(const float4*)(wp + f * 4);
                float sv0 = s_sh[i0 + i4 * 4 + 0];
                float sv1 = s_sh[i0 + i4 * 4 + 1];
                float sv2 = s_sh[i0 + i4 * 4 + 2];
                float sv3 = s_sh[i0 + i4 * 4 + 3];
                float m0[5], m1[5], m2[5], m3[5];
                float psum = 0.f;
                #pragma unroll
                for (int k = 0; k < 5; ++k) {
                    m0[k] = q[0 * 5 + k] * sv0;  psum += m0[k] * m0[k];
                    m1[k] = q[1 * 5 + k] * sv1;  psum += m1[k] * m1[k];
                    m2[k] = q[2 * 5 + k] * sv2;  psum += m2[k] * m2[k];
                    m3[k] = q[3 * 5 + k] * sv3;  psum += m3[k] * m3[k];
                }
                atomicAdd(&dm_acc[o_l], psum);
                #pragma unroll
                for (int k = 0; k < 5; ++k) {
                    union { ushort_t us[4]; uint2 u2; } p;
                    p.us[0] = f2bf(m0[k]); p.us[1] = f2bf(m1[k]);
                    p.us[2] = f2bf(m2[k]); p.us[3] = f2bf(m3[k]);
                    *(uint2*)&w_sh[(k * OM + o_l) * 32 + i4 * 4] = p.u2;
                }
            }
        }
        __syncthreads();
        #pragma unroll
        for (int kt = 0; kt < KW; ++kt) {
            short8 a[4], bf[4];
            #pragma unroll
            for (int mt = 0; mt < 4; ++mt)
                a[mt] = *(const short8*)&w_sh[(kt * OM + wm * 64 + mt * 16 + col16) * 32 + quad * 8];
            #pragma unroll
            for (int nt = 0; nt < 4; ++nt) {
                int r   = wn * 64 + nt * 16 + col16 + kt;
                int grp = quad ^ (r & 3);
                bf[nt] = *(const short8*)&x_sh[r * 32 + grp * 8];
            }
            #pragma unroll
            for (int mt = 0; mt < 4; ++mt)
                #pragma unroll
                for (int nt = 0; nt < 4; ++nt)
                    acc[mt][nt] = __builtin_amdgcn_mfma_f32_16x16x32_bf16(
                        a[mt], bf[nt], acc[mt][nt], 0, 0, 0);
        }
    }

    __syncthreads();
    if (tid < OM) dmv[tid] = rsqrtf(dm_acc[tid] + 1e-8f);
    __syncthreads();

    #pragma unroll
    for (int mt = 0; mt < 4; ++mt) {
        #pragma unroll
        for (int nt = 0; nt < 4; ++nt) {
            const int t_o = t0 + wn * 64 + nt * 16 + col16;
            #pragma unroll
            for (int reg = 0; reg < 4; ++reg) {
                const int o_l = wm * 64 + mt * 16 + quad * 4 + reg;
                float v = acc[mt][nt][reg] * dmv[o_l];
                v = (v > 0.f) ? v : 0.2f * v;
                out[((size_t)(b * COUT + o0 + o_l)) * TT + t_o] = v;
            }
        }
    }
}

// ---------------------------------------------------------------------------
extern "C" void kernel_launch(void* const* d_in, const int* in_sizes, int n_in,
                              void* d_out, int out_size, void* d_ws, size_t ws_size,
                              hipStream_t stream)
{
    const float* x       = (const float*)d_in[0];
    const float* c_trg   = (const float*)d_in[1];
    const float* style_w = (const float*)d_in[2];
    const float* style_b = (const float*)d_in[3];
    const float* weight  = (const float*)d_in[4];
    float* out = (float*)d_out;

    if (ws_size >= WMOD_BYTES) {
        // fast path: precompute modulated bf16 weights into d_ws
        ushort_t* wmod = (ushort_t*)d_ws;
        prep_kernel<<<dim3(32, 16), dim3(256), 0, stream>>>(
            c_trg, style_w, style_b, weight, wmod);
        conv_mfma_ws_kernel<<<dim3(TT / TN, COUT / OM, B_), dim3(256), 0, stream>>>(
            x, wmod, out);
    } else {
        conv_mfma_fb_kernel<<<dim3(TT / TN, COUT / OM, B_), dim3(256), 0, stream>>>(
            x, c_trg, style_w, style_b, weight, out);
    }

    hipMemcpyAsync(out + (size_t)B_ * COUT * TT, c_trg,
                   (size_t)B_ * SPK * sizeof(float),
                   hipMemcpyDeviceToDevice, stream);
}